// Round 1
// baseline (1123.382 us; speedup 1.0000x reference)
//
#include <hip/hip_runtime.h>

#define TT 2048     // tokens
#define HD 2048     // hidden dim
#define FD 1408     // expert intermediate
#define NE 16       // routed experts
#define NG 18       // routed + 2 shared pseudo-experts

typedef __attribute__((ext_vector_type(4))) float f32x4;
typedef __attribute__((ext_vector_type(8))) short short8;
typedef __attribute__((ext_vector_type(8))) __bf16 bf16x8;
typedef __attribute__((ext_vector_type(4))) unsigned short u16x4;
typedef __attribute__((ext_vector_type(8))) unsigned short u16x8;

__device__ __forceinline__ unsigned short f2bf(float f) {
  unsigned u = __builtin_bit_cast(unsigned, f);
  u += 0x7fffu + ((u >> 16) & 1u);   // RNE
  return (unsigned short)(u >> 16);
}

// MFMA wrapper that compiles whether the gfx950 builtin takes short8 or bf16x8.
template <typename T>
__device__ __forceinline__ auto mfma_try(T a, T b, f32x4 c, int)
    -> decltype(__builtin_amdgcn_mfma_f32_16x16x32_bf16(a, b, c, 0, 0, 0)) {
  return __builtin_amdgcn_mfma_f32_16x16x32_bf16(a, b, c, 0, 0, 0);
}
template <typename T, typename BV = bf16x8>
__device__ __forceinline__ f32x4 mfma_try(T a, T b, f32x4 c, long) {
  BV aa = __builtin_bit_cast(BV, a);
  BV bb = __builtin_bit_cast(BV, b);
  return __builtin_amdgcn_mfma_f32_16x16x32_bf16(aa, bb, c, 0, 0, 0);
}
__device__ __forceinline__ f32x4 mfma16(short8 a, short8 b, f32x4 c) {
  return mfma_try(a, b, c, 0);
}

// Swizzled index into a [rows][32] ushort LDS tile (16B-chunk XOR swizzle).
__device__ __forceinline__ int swz(int r, int k) {
  return r * 32 + ((((k >> 3) ^ r) & 3) << 3) + (k & 7);
}

// ---------------- gate: logits -> softmax -> top4 -> dense weights ----------
__global__ void gate_kernel(const float* __restrict__ x, const float* __restrict__ gw,
                            float* __restrict__ dense_w) {
  int wid = threadIdx.x >> 6;
  int lane = threadIdx.x & 63;
  int t = blockIdx.x * 4 + wid;
  if (t >= TT) return;
  const float* xr = x + (size_t)t * HD;
  float acc[NE];
#pragma unroll
  for (int e = 0; e < NE; ++e) acc[e] = 0.f;
  for (int h = lane; h < HD; h += 64) {
    float xv = xr[h];
#pragma unroll
    for (int e = 0; e < NE; ++e) acc[e] += xv * gw[e * HD + h];
  }
#pragma unroll
  for (int e = 0; e < NE; ++e) {
    float v = acc[e];
#pragma unroll
    for (int s = 32; s > 0; s >>= 1) v += __shfl_xor(v, s, 64);
    acc[e] = v;
  }
  float mx = acc[0];
#pragma unroll
  for (int e = 1; e < NE; ++e) mx = fmaxf(mx, acc[e]);
  float p[NE]; float sum = 0.f;
#pragma unroll
  for (int e = 0; e < NE; ++e) { p[e] = __expf(acc[e] - mx); sum += p[e]; }
  float inv = 1.f / sum;
#pragma unroll
  for (int e = 0; e < NE; ++e) p[e] *= inv;
  unsigned chosen = 0;
#pragma unroll
  for (int k = 0; k < 4; ++k) {
    int bi = 0; float bv = -1.f;
#pragma unroll
    for (int e = 0; e < NE; ++e) {
      bool ok = !((chosen >> e) & 1) && (p[e] > bv);
      bv = ok ? p[e] : bv;
      bi = ok ? e : bi;
    }
    chosen |= 1u << bi;
  }
  if (lane < NE)
    dense_w[t * NE + lane] = ((chosen >> lane) & 1) ? p[lane] : 0.f;
}

// ---------------- stable per-group token lists ------------------------------
__global__ void build_lists(const float* __restrict__ dense_w, int* __restrict__ tok,
                            float* __restrict__ scale, int* __restrict__ counts) {
  int g = blockIdx.x;
  int lane = threadIdx.x;  // blockDim = 64
  if (g >= NE) {           // shared pseudo-experts: identity lists, weight 1
    for (int i = lane; i < TT; i += 64) { tok[g * TT + i] = i; scale[g * TT + i] = 1.f; }
    if (lane == 0) counts[g] = TT;
    return;
  }
  int base = 0;
  for (int c0 = 0; c0 < TT; c0 += 64) {
    int t = c0 + lane;
    float w = dense_w[t * NE + g];
    bool pred = w > 0.f;
    unsigned long long b = __ballot(pred);
    if (pred) {
      int pos = base + __popcll(b & ((1ull << lane) - 1ull));
      tok[g * TT + pos] = t;
      scale[g * TT + pos] = w;
    }
    base += __popcll(b);
  }
  if (lane == 0) counts[g] = base;
}

__global__ void prefix_kernel(const int* __restrict__ counts, int* __restrict__ rowOff) {
  if (threadIdx.x == 0) {
    int s = 0;
    for (int g = 0; g < NE; ++g) { rowOff[g] = s; s += counts[g]; }
    rowOff[16] = 4 * TT;         // shared halves at fixed offsets
    rowOff[17] = 4 * TT + TT;
  }
}

// ---------------- grouped GEMM 1: A=silu(xWg)*(xWu)*w  -> Abuf (bf16) -------
__global__ __launch_bounds__(512, 2) void gemm1_kernel(
    const float* __restrict__ x,
    const float* __restrict__ w_gate, const float* __restrict__ w_up,
    const float* __restrict__ ws_gate, const float* __restrict__ ws_up,
    const int* __restrict__ tok, const float* __restrict__ scale,
    const int* __restrict__ counts, const int* __restrict__ rowOff,
    unsigned short* __restrict__ Abuf) {
  const int g = blockIdx.z, cb = blockIdx.y, rb = blockIdx.x;
  const int count = counts[g];
  if (rb * 256 >= count) return;

  const float *Bg, *Bu; int ldb, bcol0;
  if (g < NE) {
    size_t o = (size_t)g * HD * FD;
    Bg = w_gate + o; Bu = w_up + o; ldb = FD; bcol0 = cb * 128;
  } else {
    Bg = ws_gate; Bu = ws_up; ldb = 2 * FD; bcol0 = (g - NE) * FD + cb * 128;
  }

  __shared__ __align__(16) unsigned short sA[2][256 * 32];
  __shared__ __align__(16) unsigned short sG[2][128 * 32];
  __shared__ __align__(16) unsigned short sU[2][128 * 32];

  const int tid = threadIdx.x;
  const int lane = tid & 63;
  const int wid = tid >> 6;
  const int wr = (wid >> 1) << 6;
  const int wc = (wid & 1) << 6;

  // A staging: 4 gathered rows x one float4 k-group per thread
  const int kg = tid & 7;
  const int rbase = (tid >> 3) << 2;
  const float* aptr[4];
#pragma unroll
  for (int j = 0; j < 4; ++j) {
    int i = rb * 256 + rbase + j;
    int t = (i < count) ? tok[g * TT + i] : 0;
    aptr[j] = x + (size_t)t * HD + kg * 4;
  }
  // B staging: one column, 8 consecutive k per thread (coalesced across lanes)
  const int bc = tid & 127;
  const int kb = (tid >> 7) << 3;
  const float* gp = Bg + (size_t)kb * ldb + bcol0 + bc;
  const float* up = Bu + (size_t)kb * ldb + bcol0 + bc;

  const f32x4 fz = {0.f, 0.f, 0.f, 0.f};
  f32x4 accg[4][4], accu[4][4];
#pragma unroll
  for (int m = 0; m < 4; ++m)
#pragma unroll
    for (int n = 0; n < 4; ++n) { accg[m][n] = fz; accu[m][n] = fz; }

  f32x4 av[4]; float bgv[8], buv[8];

  auto LOAD = [&](int k0) {
#pragma unroll
    for (int j = 0; j < 4; ++j) av[j] = *(const f32x4*)(aptr[j] + k0);
#pragma unroll
    for (int j = 0; j < 8; ++j) {
      bgv[j] = gp[(size_t)(k0 + j) * ldb];
      buv[j] = up[(size_t)(k0 + j) * ldb];
    }
  };
  auto STORE = [&](int b) {
#pragma unroll
    for (int j = 0; j < 4; ++j) {
      int r = rbase + j;
      u16x4 h;
      h.x = f2bf(av[j].x); h.y = f2bf(av[j].y); h.z = f2bf(av[j].z); h.w = f2bf(av[j].w);
      *(u16x4*)&sA[b][r * 32 + ((((kg >> 1) ^ r) & 3) << 3) + ((kg & 1) << 2)] = h;
    }
    u16x8 hg, hu;
#pragma unroll
    for (int j = 0; j < 8; ++j) { hg[j] = f2bf(bgv[j]); hu[j] = f2bf(buv[j]); }
    int bi = bc * 32 + ((((kb >> 3) ^ bc) & 3) << 3);
    *(u16x8*)&sG[b][bi] = hg;
    *(u16x8*)&sU[b][bi] = hu;
  };
  auto COMPUTE = [&](int b) {
    const int ksel = lane >> 4;
    short8 bg4[4], bu4[4];
#pragma unroll
    for (int n = 0; n < 4; ++n) {
      int c = wc + n * 16 + (lane & 15);
      int idx = c * 32 + (((ksel ^ c) & 3) << 3);
      bg4[n] = *(const short8*)&sG[b][idx];
      bu4[n] = *(const short8*)&sU[b][idx];
    }
#pragma unroll
    for (int m = 0; m < 4; ++m) {
      int r = wr + m * 16 + (lane & 15);
      short8 a = *(const short8*)&sA[b][r * 32 + (((ksel ^ r) & 3) << 3)];
#pragma unroll
      for (int n = 0; n < 4; ++n) {
        accg[m][n] = mfma16(a, bg4[n], accg[m][n]);
        accu[m][n] = mfma16(a, bu4[n], accu[m][n]);
      }
    }
  };

  LOAD(0);
  STORE(0);
  __syncthreads();
  const int NK = HD / 32;
  for (int s = 0; s < NK; ++s) {
    int cur = s & 1;
    if (s + 1 < NK) LOAD((s + 1) * 32);
    COMPUTE(cur);
    if (s + 1 < NK) STORE(cur ^ 1);
    __syncthreads();
  }

  const int rowBase = rowOff[g] + rb * 256;
#pragma unroll
  for (int m = 0; m < 4; ++m)
#pragma unroll
    for (int r = 0; r < 4; ++r) {
      int rl = wr + m * 16 + ((lane >> 4) << 2) + r;
      int gi = rb * 256 + rl;
      if (gi < count) {
        float sc = scale[g * TT + gi];
#pragma unroll
        for (int n = 0; n < 4; ++n) {
          int cl = wc + n * 16 + (lane & 15);
          float gv = accg[m][n][r], uv = accu[m][n][r];
          float a = gv / (1.f + __expf(-gv)) * uv * sc;
          Abuf[(size_t)(rowBase + rl) * FD + cb * 128 + cl] = f2bf(a);
        }
      }
    }
}

// ---------------- grouped GEMM 2: out[tok] += Abuf @ Wdown ------------------
__global__ __launch_bounds__(512, 2) void gemm2_kernel(
    const unsigned short* __restrict__ Abuf,
    const float* __restrict__ w_down, const float* __restrict__ ws_down,
    const int* __restrict__ tok, const int* __restrict__ counts,
    const int* __restrict__ rowOff, float* __restrict__ out) {
  const int g = blockIdx.z, cb = blockIdx.y, rb = blockIdx.x;
  const int count = counts[g];
  if (rb * 256 >= count) return;

  const float* Bd = (g < NE) ? (w_down + (size_t)g * FD * HD)
                             : (ws_down + (size_t)(g - NE) * FD * HD);

  __shared__ __align__(16) unsigned short sA[2][256 * 32];
  __shared__ __align__(16) unsigned short sB[2][128 * 32];

  const int tid = threadIdx.x;
  const int lane = tid & 63;
  const int wid = tid >> 6;
  const int wr = (wid >> 1) << 6;
  const int wc = (wid & 1) << 6;

  const int rowBase = rowOff[g] + rb * 256;

  const int kg = tid & 3;      // 8-k group
  const int rr = tid >> 2;     // 0..127, rows rr and rr+128
  const unsigned short* ap0 = Abuf + (size_t)(rowBase + rr) * FD + kg * 8;
  const unsigned short* ap1 = ap0 + (size_t)128 * FD;

  const int bc = tid & 127;
  const int kb = (tid >> 7) << 3;
  const float* bp = Bd + (size_t)kb * HD + cb * 128 + bc;

  const f32x4 fz = {0.f, 0.f, 0.f, 0.f};
  f32x4 acc[4][4];
#pragma unroll
  for (int m = 0; m < 4; ++m)
#pragma unroll
    for (int n = 0; n < 4; ++n) acc[m][n] = fz;

  u16x8 a0, a1; float bv[8];
  auto LOAD = [&](int k0) {
    a0 = *(const u16x8*)(ap0 + k0);
    a1 = *(const u16x8*)(ap1 + k0);
#pragma unroll
    for (int j = 0; j < 8; ++j) bv[j] = bp[(size_t)(k0 + j) * HD];
  };
  auto STORE = [&](int b) {
    int sw = ((kg ^ rr) & 3) << 3;  // (rr+128)&3 == rr&3
    *(u16x8*)&sA[b][rr * 32 + sw] = a0;
    *(u16x8*)&sA[b][(rr + 128) * 32 + sw] = a1;
    u16x8 hb;
#pragma unroll
    for (int j = 0; j < 8; ++j) hb[j] = f2bf(bv[j]);
    *(u16x8*)&sB[b][bc * 32 + ((((kb >> 3) ^ bc) & 3) << 3)] = hb;
  };
  auto COMPUTE = [&](int b) {
    const int ksel = lane >> 4;
    short8 b4[4];
#pragma unroll
    for (int n = 0; n < 4; ++n) {
      int c = wc + n * 16 + (lane & 15);
      b4[n] = *(const short8*)&sB[b][c * 32 + (((ksel ^ c) & 3) << 3)];
    }
#pragma unroll
    for (int m = 0; m < 4; ++m) {
      int r = wr + m * 16 + (lane & 15);
      short8 a = *(const short8*)&sA[b][r * 32 + (((ksel ^ r) & 3) << 3)];
#pragma unroll
      for (int n = 0; n < 4; ++n) acc[m][n] = mfma16(a, b4[n], acc[m][n]);
    }
  };

  LOAD(0);
  STORE(0);
  __syncthreads();
  const int NK = FD / 32;  // 44
  for (int s = 0; s < NK; ++s) {
    int cur = s & 1;
    if (s + 1 < NK) LOAD((s + 1) * 32);
    COMPUTE(cur);
    if (s + 1 < NK) STORE(cur ^ 1);
    __syncthreads();
  }

#pragma unroll
  for (int m = 0; m < 4; ++m)
#pragma unroll
    for (int r = 0; r < 4; ++r) {
      int rl = wr + m * 16 + ((lane >> 4) << 2) + r;
      int gi = rb * 256 + rl;
      if (gi < count) {
        int t = tok[g * TT + gi];
        float* op = out + (size_t)t * HD + cb * 128;
#pragma unroll
        for (int n = 0; n < 4; ++n)
          atomicAdd(op + wc + n * 16 + (lane & 15), acc[m][n][r]);
      }
    }
}

// ---------------------------------------------------------------------------
extern "C" void kernel_launch(void* const* d_in, const int* in_sizes, int n_in,
                              void* d_out, int out_size, void* d_ws, size_t ws_size,
                              hipStream_t stream) {
  const float* x      = (const float*)d_in[0];
  const float* gw     = (const float*)d_in[1];
  const float* w_gate = (const float*)d_in[2];
  const float* w_up   = (const float*)d_in[3];
  const float* w_down = (const float*)d_in[4];
  const float* wsg    = (const float*)d_in[5];
  const float* wsu    = (const float*)d_in[6];
  const float* wsd    = (const float*)d_in[7];
  float* out = (float*)d_out;

  char* ws = (char*)d_ws;
  float* dense_w = (float*)(ws);                       // 2048*16*4   = 128KB
  int*   tok     = (int*)(ws + (140 << 10));           // 18*2048*4   = 144KB
  float* scale   = (float*)(ws + (290 << 10));         // 18*2048*4   = 144KB
  int*   counts  = (int*)(ws + (440 << 10));           // 18*4
  int*   rowOff  = (int*)(ws + (441 << 10));           // 18*4
  unsigned short* Abuf = (unsigned short*)(ws + (1 << 20));  // 12288*1408*2 = 33MB

  hipMemsetAsync(d_out, 0, (size_t)out_size * sizeof(float), stream);
  gate_kernel<<<TT / 4, 256, 0, stream>>>(x, gw, dense_w);
  build_lists<<<NG, 64, 0, stream>>>(dense_w, tok, scale, counts);
  prefix_kernel<<<1, 64, 0, stream>>>(counts, rowOff);
  gemm1_kernel<<<dim3(8, FD / 128, NG), 512, 0, stream>>>(
      x, w_gate, w_up, wsg, wsu, tok, scale, counts, rowOff, Abuf);
  gemm2_kernel<<<dim3(8, HD / 128, NG), 512, 0, stream>>>(
      Abuf, w_down, wsd, tok, counts, rowOff, out);
}

// Round 2
// 1090.708 us; speedup vs baseline: 1.0300x; 1.0300x over previous
//
#include <hip/hip_runtime.h>

#define TT 2048     // tokens
#define HD 2048     // hidden dim
#define FD 1408     // expert intermediate
#define NE 16       // routed experts
#define NG 18       // routed + 2 shared pseudo-experts

typedef __attribute__((ext_vector_type(4))) float f32x4;
typedef __attribute__((ext_vector_type(8))) short short8;
typedef __attribute__((ext_vector_type(8))) __bf16 bf16x8;
typedef __attribute__((ext_vector_type(4))) unsigned short u16x4;
typedef __attribute__((ext_vector_type(8))) unsigned short u16x8;

__device__ __forceinline__ unsigned short f2bf(float f) {
  unsigned u = __builtin_bit_cast(unsigned, f);
  u += 0x7fffu + ((u >> 16) & 1u);   // RNE
  return (unsigned short)(u >> 16);
}

// MFMA wrapper that compiles whether the gfx950 builtin takes short8 or bf16x8.
template <typename T>
__device__ __forceinline__ auto mfma_try(T a, T b, f32x4 c, int)
    -> decltype(__builtin_amdgcn_mfma_f32_16x16x32_bf16(a, b, c, 0, 0, 0)) {
  return __builtin_amdgcn_mfma_f32_16x16x32_bf16(a, b, c, 0, 0, 0);
}
template <typename T, typename BV = bf16x8>
__device__ __forceinline__ f32x4 mfma_try(T a, T b, f32x4 c, long) {
  BV aa = __builtin_bit_cast(BV, a);
  BV bb = __builtin_bit_cast(BV, b);
  return __builtin_amdgcn_mfma_f32_16x16x32_bf16(aa, bb, c, 0, 0, 0);
}
__device__ __forceinline__ f32x4 mfma16(short8 a, short8 b, f32x4 c) {
  return mfma_try(a, b, c, 0);
}

// ---------------- gate: logits -> softmax -> top4 -> dense weights ----------
__global__ void gate_kernel(const float* __restrict__ x, const float* __restrict__ gw,
                            float* __restrict__ dense_w) {
  int wid = threadIdx.x >> 6;
  int lane = threadIdx.x & 63;
  int t = blockIdx.x * 4 + wid;
  if (t >= TT) return;
  const float* xr = x + (size_t)t * HD;
  float acc[NE];
#pragma unroll
  for (int e = 0; e < NE; ++e) acc[e] = 0.f;
  for (int h = lane; h < HD; h += 64) {
    float xv = xr[h];
#pragma unroll
    for (int e = 0; e < NE; ++e) acc[e] += xv * gw[e * HD + h];
  }
#pragma unroll
  for (int e = 0; e < NE; ++e) {
    float v = acc[e];
#pragma unroll
    for (int s = 32; s > 0; s >>= 1) v += __shfl_xor(v, s, 64);
    acc[e] = v;
  }
  float mx = acc[0];
#pragma unroll
  for (int e = 1; e < NE; ++e) mx = fmaxf(mx, acc[e]);
  float p[NE]; float sum = 0.f;
#pragma unroll
  for (int e = 0; e < NE; ++e) { p[e] = __expf(acc[e] - mx); sum += p[e]; }
  float inv = 1.f / sum;
#pragma unroll
  for (int e = 0; e < NE; ++e) p[e] *= inv;
  unsigned chosen = 0;
#pragma unroll
  for (int k = 0; k < 4; ++k) {
    int bi = 0; float bv = -1.f;
#pragma unroll
    for (int e = 0; e < NE; ++e) {
      bool ok = !((chosen >> e) & 1) && (p[e] > bv);
      bv = ok ? p[e] : bv;
      bi = ok ? e : bi;
    }
    chosen |= 1u << bi;
  }
  if (lane < NE)
    dense_w[t * NE + lane] = ((chosen >> lane) & 1) ? p[lane] : 0.f;
}

// ---------------- stable per-group token lists ------------------------------
__global__ void build_lists(const float* __restrict__ dense_w, int* __restrict__ tok,
                            float* __restrict__ scale, int* __restrict__ counts) {
  int g = blockIdx.x;
  int lane = threadIdx.x;  // blockDim = 64
  if (g >= NE) {           // shared pseudo-experts: identity lists, weight 1
    for (int i = lane; i < TT; i += 64) { tok[g * TT + i] = i; scale[g * TT + i] = 1.f; }
    if (lane == 0) counts[g] = TT;
    return;
  }
  int base = 0;
  for (int c0 = 0; c0 < TT; c0 += 64) {
    int t = c0 + lane;
    float w = dense_w[t * NE + g];
    bool pred = w > 0.f;
    unsigned long long b = __ballot(pred);
    if (pred) {
      int pos = base + __popcll(b & ((1ull << lane) - 1ull));
      tok[g * TT + pos] = t;
      scale[g * TT + pos] = w;
    }
    base += __popcll(b);
  }
  if (lane == 0) counts[g] = base;
}

__global__ void prefix_kernel(const int* __restrict__ counts, int* __restrict__ rowOff) {
  if (threadIdx.x == 0) {
    int s = 0;
    for (int g = 0; g < NE; ++g) { rowOff[g] = s; s += counts[g]; }
    rowOff[16] = 4 * TT;         // shared halves at fixed offsets
    rowOff[17] = 4 * TT + TT;
  }
}

// ---------------- prep: fp32 -> bf16 streaming convert ----------------------
__global__ void cvt_bf16_kernel(const float* __restrict__ in,
                                unsigned short* __restrict__ out, int n4) {
  int i = blockIdx.x * blockDim.x + threadIdx.x;
  if (i < n4) {
    f32x4 v = ((const f32x4*)in)[i];
    u16x4 h;
    h.x = f2bf(v.x); h.y = f2bf(v.y); h.z = f2bf(v.z); h.w = f2bf(v.w);
    ((u16x4*)out)[i] = h;
  }
}

// ---------------- prep: fp32 [B][R][C] -> bf16 [B][C][R] tiled transpose ----
__global__ __launch_bounds__(256) void transpose_bf16_kernel(
    const float* __restrict__ in, unsigned short* __restrict__ out, int R, int C) {
  __shared__ float tile[64 * 65];
  const size_t base = (size_t)blockIdx.z * R * C;
  const int c0 = blockIdx.x * 64, r0 = blockIdx.y * 64;
  const int tid = threadIdx.x;
  const int rr = tid >> 4;          // 0..15
  const int c4 = (tid & 15) * 4;
#pragma unroll
  for (int it = 0; it < 4; ++it) {
    int r = rr + it * 16;
    f32x4 v = *(const f32x4*)(in + base + (size_t)(r0 + r) * C + c0 + c4);
#pragma unroll
    for (int i = 0; i < 4; ++i) tile[(c4 + i) * 65 + r] = v[i];
  }
  __syncthreads();
  const int cl = tid >> 3;          // 0..31
  const int rc = (tid & 7) * 8;
#pragma unroll
  for (int it = 0; it < 2; ++it) {
    int c = cl + it * 32;
    u16x8 h;
#pragma unroll
    for (int j = 0; j < 8; ++j) h[j] = f2bf(tile[c * 65 + rc + j]);
    *(u16x8*)(out + base + (size_t)(c0 + c) * R + r0 + rc) = h;
  }
}

// ============================================================================
// FAST PATH (bf16 pre-transposed weights; all loads 16B, no in-loop converts)
// ============================================================================
__global__ __launch_bounds__(512, 2) void gemm1_fast(
    const unsigned short* __restrict__ xb,
    const unsigned short* __restrict__ wgT, const unsigned short* __restrict__ wuT,
    const unsigned short* __restrict__ wsgT, const unsigned short* __restrict__ wsuT,
    const int* __restrict__ tok, const float* __restrict__ scale,
    const int* __restrict__ counts, const int* __restrict__ rowOff,
    unsigned short* __restrict__ Abuf) {
  const int g = blockIdx.z, cb = blockIdx.y, rb = blockIdx.x;
  const int count = counts[g];
  if (rb * 256 >= count) return;

  __shared__ __align__(16) unsigned short sA[2][256 * 32];
  __shared__ __align__(16) unsigned short sG[2][128 * 32];
  __shared__ __align__(16) unsigned short sU[2][128 * 32];

  const int tid = threadIdx.x;
  const int lane = tid & 63;
  const int wid = tid >> 6;
  const int wr = (wid >> 1) << 6;
  const int wc = (wid & 1) << 6;

  // A staging: one gathered row per thread-pair, two 16B chunks each
  const int ar = tid >> 1;               // 0..255
  const int akc = (tid & 1) * 2;         // k-chunk 0 or 2 (chunk = 8 bf16)
  {
  }
  int gi0 = rb * 256 + ar;
  int t0 = (gi0 < count) ? tok[g * TT + gi0] : 0;
  const unsigned short* aptr = xb + (size_t)t0 * HD + akc * 8;

  // B staging: one column per 4 threads, one 16B chunk each
  const int col = tid >> 2;              // 0..127
  const int bkc = tid & 3;
  const unsigned short *gp, *up;
  if (g < NE) {
    size_t o = (size_t)g * FD * HD + (size_t)(cb * 128 + col) * HD;
    gp = wgT + o; up = wuT + o;
  } else {
    size_t o = (size_t)((g - NE) * FD + cb * 128 + col) * HD;
    gp = wsgT + o; up = wsuT + o;
  }
  gp += bkc * 8; up += bkc * 8;

  const f32x4 fz = {0.f, 0.f, 0.f, 0.f};
  f32x4 accg[4][4], accu[4][4];
#pragma unroll
  for (int m = 0; m < 4; ++m)
#pragma unroll
    for (int n = 0; n < 4; ++n) { accg[m][n] = fz; accu[m][n] = fz; }

  u16x8 a0, a1, bg, bu;
  auto LOAD = [&](int k0) {
    a0 = *(const u16x8*)(aptr + k0);
    a1 = *(const u16x8*)(aptr + k0 + 8);
    bg = *(const u16x8*)(gp + k0);
    bu = *(const u16x8*)(up + k0);
  };
  auto STORE = [&](int b) {
    *(u16x8*)&sA[b][ar * 32 + ((akc ^ ar) & 3) * 8] = a0;
    *(u16x8*)&sA[b][ar * 32 + (((akc + 1) ^ ar) & 3) * 8] = a1;
    *(u16x8*)&sG[b][col * 32 + ((bkc ^ col) & 3) * 8] = bg;
    *(u16x8*)&sU[b][col * 32 + ((bkc ^ col) & 3) * 8] = bu;
  };
  auto COMPUTE = [&](int b) {
    const int ksel = lane >> 4;
    short8 bg4[4], bu4[4];
#pragma unroll
    for (int n = 0; n < 4; ++n) {
      int c = wc + n * 16 + (lane & 15);
      int idx = c * 32 + (((ksel ^ c) & 3) << 3);
      bg4[n] = *(const short8*)&sG[b][idx];
      bu4[n] = *(const short8*)&sU[b][idx];
    }
#pragma unroll
    for (int m = 0; m < 4; ++m) {
      int r = wr + m * 16 + (lane & 15);
      short8 a = *(const short8*)&sA[b][r * 32 + (((ksel ^ r) & 3) << 3)];
#pragma unroll
      for (int n = 0; n < 4; ++n) {
        accg[m][n] = mfma16(a, bg4[n], accg[m][n]);
        accu[m][n] = mfma16(a, bu4[n], accu[m][n]);
      }
    }
  };

  LOAD(0);
  STORE(0);
  __syncthreads();
  const int NK = HD / 32;
  for (int s = 0; s < NK; ++s) {
    int cur = s & 1;
    if (s + 1 < NK) LOAD((s + 1) * 32);
    COMPUTE(cur);
    if (s + 1 < NK) STORE(cur ^ 1);
    __syncthreads();
  }

  const int rowBase = rowOff[g] + rb * 256;
#pragma unroll
  for (int m = 0; m < 4; ++m)
#pragma unroll
    for (int r = 0; r < 4; ++r) {
      int rl = wr + m * 16 + ((lane >> 4) << 2) + r;
      int gi = rb * 256 + rl;
      if (gi < count) {
        float sc = scale[g * TT + gi];
#pragma unroll
        for (int n = 0; n < 4; ++n) {
          int cl = wc + n * 16 + (lane & 15);
          float gv = accg[m][n][r], uv = accu[m][n][r];
          float a = gv / (1.f + __expf(-gv)) * uv * sc;
          Abuf[(size_t)(rowBase + rl) * FD + cb * 128 + cl] = f2bf(a);
        }
      }
    }
}

__global__ __launch_bounds__(512, 2) void gemm2_fast(
    const unsigned short* __restrict__ Abuf,
    const unsigned short* __restrict__ wdT, const unsigned short* __restrict__ wsdT,
    const int* __restrict__ tok, const int* __restrict__ counts,
    const int* __restrict__ rowOff, float* __restrict__ out) {
  const int g = blockIdx.z, cb = blockIdx.y, rb = blockIdx.x;
  const int count = counts[g];
  if (rb * 256 >= count) return;

  __shared__ __align__(16) unsigned short sA[2][256 * 32];
  __shared__ __align__(16) unsigned short sB[2][128 * 32];

  const int tid = threadIdx.x;
  const int lane = tid & 63;
  const int wid = tid >> 6;
  const int wr = (wid >> 1) << 6;
  const int wc = (wid & 1) << 6;

  const int rowBase = rowOff[g] + rb * 256;

  const int ar = tid >> 1;               // 0..255
  const int akc = (tid & 1) * 2;
  const unsigned short* aptr = Abuf + (size_t)(rowBase + ar) * FD + akc * 8;

  const int col = tid >> 2;              // 0..127
  const int bkc = tid & 3;
  const unsigned short* bp;
  if (g < NE)
    bp = wdT + (size_t)g * HD * FD + (size_t)(cb * 128 + col) * FD;
  else
    bp = wsdT + (size_t)(cb * 128 + col) * (2 * FD) + (size_t)(g - NE) * FD;
  bp += bkc * 8;

  const f32x4 fz = {0.f, 0.f, 0.f, 0.f};
  f32x4 acc[4][4];
#pragma unroll
  for (int m = 0; m < 4; ++m)
#pragma unroll
    for (int n = 0; n < 4; ++n) acc[m][n] = fz;

  u16x8 a0, a1, bv;
  auto LOAD = [&](int k0) {
    a0 = *(const u16x8*)(aptr + k0);
    a1 = *(const u16x8*)(aptr + k0 + 8);
    bv = *(const u16x8*)(bp + k0);
  };
  auto STORE = [&](int b) {
    *(u16x8*)&sA[b][ar * 32 + ((akc ^ ar) & 3) * 8] = a0;
    *(u16x8*)&sA[b][ar * 32 + (((akc + 1) ^ ar) & 3) * 8] = a1;
    *(u16x8*)&sB[b][col * 32 + ((bkc ^ col) & 3) * 8] = bv;
  };
  auto COMPUTE = [&](int b) {
    const int ksel = lane >> 4;
    short8 b4[4];
#pragma unroll
    for (int n = 0; n < 4; ++n) {
      int c = wc + n * 16 + (lane & 15);
      b4[n] = *(const short8*)&sB[b][c * 32 + (((ksel ^ c) & 3) << 3)];
    }
#pragma unroll
    for (int m = 0; m < 4; ++m) {
      int r = wr + m * 16 + (lane & 15);
      short8 a = *(const short8*)&sA[b][r * 32 + (((ksel ^ r) & 3) << 3)];
#pragma unroll
      for (int n = 0; n < 4; ++n) acc[m][n] = mfma16(a, b4[n], acc[m][n]);
    }
  };

  LOAD(0);
  STORE(0);
  __syncthreads();
  const int NK = FD / 32;  // 44
  for (int s = 0; s < NK; ++s) {
    int cur = s & 1;
    if (s + 1 < NK) LOAD((s + 1) * 32);
    COMPUTE(cur);
    if (s + 1 < NK) STORE(cur ^ 1);
    __syncthreads();
  }

#pragma unroll
  for (int m = 0; m < 4; ++m)
#pragma unroll
    for (int r = 0; r < 4; ++r) {
      int rl = wr + m * 16 + ((lane >> 4) << 2) + r;
      int gi = rb * 256 + rl;
      if (gi < count) {
        int t = tok[g * TT + gi];
        float* op = out + (size_t)t * HD + cb * 128;
#pragma unroll
        for (int n = 0; n < 4; ++n)
          atomicAdd(op + wc + n * 16 + (lane & 15), acc[m][n][r]);
      }
    }
}

// ============================================================================
// FALLBACK PATH (original fp32-weight kernels, used when ws too small)
// ============================================================================
__global__ __launch_bounds__(512, 2) void gemm1_kernel(
    const float* __restrict__ x,
    const float* __restrict__ w_gate, const float* __restrict__ w_up,
    const float* __restrict__ ws_gate, const float* __restrict__ ws_up,
    const int* __restrict__ tok, const float* __restrict__ scale,
    const int* __restrict__ counts, const int* __restrict__ rowOff,
    unsigned short* __restrict__ Abuf) {
  const int g = blockIdx.z, cb = blockIdx.y, rb = blockIdx.x;
  const int count = counts[g];
  if (rb * 256 >= count) return;

  const float *Bg, *Bu; int ldb, bcol0;
  if (g < NE) {
    size_t o = (size_t)g * HD * FD;
    Bg = w_gate + o; Bu = w_up + o; ldb = FD; bcol0 = cb * 128;
  } else {
    Bg = ws_gate; Bu = ws_up; ldb = 2 * FD; bcol0 = (g - NE) * FD + cb * 128;
  }

  __shared__ __align__(16) unsigned short sA[2][256 * 32];
  __shared__ __align__(16) unsigned short sG[2][128 * 32];
  __shared__ __align__(16) unsigned short sU[2][128 * 32];

  const int tid = threadIdx.x;
  const int lane = tid & 63;
  const int wid = tid >> 6;
  const int wr = (wid >> 1) << 6;
  const int wc = (wid & 1) << 6;

  const int kg = tid & 7;
  const int rbase = (tid >> 3) << 2;
  const float* aptr[4];
#pragma unroll
  for (int j = 0; j < 4; ++j) {
    int i = rb * 256 + rbase + j;
    int t = (i < count) ? tok[g * TT + i] : 0;
    aptr[j] = x + (size_t)t * HD + kg * 4;
  }
  const int bc = tid & 127;
  const int kb = (tid >> 7) << 3;
  const float* gp = Bg + (size_t)kb * ldb + bcol0 + bc;
  const float* up = Bu + (size_t)kb * ldb + bcol0 + bc;

  const f32x4 fz = {0.f, 0.f, 0.f, 0.f};
  f32x4 accg[4][4], accu[4][4];
#pragma unroll
  for (int m = 0; m < 4; ++m)
#pragma unroll
    for (int n = 0; n < 4; ++n) { accg[m][n] = fz; accu[m][n] = fz; }

  f32x4 av[4]; float bgv[8], buv[8];

  auto LOAD = [&](int k0) {
#pragma unroll
    for (int j = 0; j < 4; ++j) av[j] = *(const f32x4*)(aptr[j] + k0);
#pragma unroll
    for (int j = 0; j < 8; ++j) {
      bgv[j] = gp[(size_t)(k0 + j) * ldb];
      buv[j] = up[(size_t)(k0 + j) * ldb];
    }
  };
  auto STORE = [&](int b) {
#pragma unroll
    for (int j = 0; j < 4; ++j) {
      int r = rbase + j;
      u16x4 h;
      h.x = f2bf(av[j].x); h.y = f2bf(av[j].y); h.z = f2bf(av[j].z); h.w = f2bf(av[j].w);
      *(u16x4*)&sA[b][r * 32 + ((((kg >> 1) ^ r) & 3) << 3) + ((kg & 1) << 2)] = h;
    }
    u16x8 hg, hu;
#pragma unroll
    for (int j = 0; j < 8; ++j) { hg[j] = f2bf(bgv[j]); hu[j] = f2bf(buv[j]); }
    int bi = bc * 32 + ((((kb >> 3) ^ bc) & 3) << 3);
    *(u16x8*)&sG[b][bi] = hg;
    *(u16x8*)&sU[b][bi] = hu;
  };
  auto COMPUTE = [&](int b) {
    const int ksel = lane >> 4;
    short8 bg4[4], bu4[4];
#pragma unroll
    for (int n = 0; n < 4; ++n) {
      int c = wc + n * 16 + (lane & 15);
      int idx = c * 32 + (((ksel ^ c) & 3) << 3);
      bg4[n] = *(const short8*)&sG[b][idx];
      bu4[n] = *(const short8*)&sU[b][idx];
    }
#pragma unroll
    for (int m = 0; m < 4; ++m) {
      int r = wr + m * 16 + (lane & 15);
      short8 a = *(const short8*)&sA[b][r * 32 + (((ksel ^ r) & 3) << 3)];
#pragma unroll
      for (int n = 0; n < 4; ++n) {
        accg[m][n] = mfma16(a, bg4[n], accg[m][n]);
        accu[m][n] = mfma16(a, bu4[n], accu[m][n]);
      }
    }
  };

  LOAD(0);
  STORE(0);
  __syncthreads();
  const int NK = HD / 32;
  for (int s = 0; s < NK; ++s) {
    int cur = s & 1;
    if (s + 1 < NK) LOAD((s + 1) * 32);
    COMPUTE(cur);
    if (s + 1 < NK) STORE(cur ^ 1);
    __syncthreads();
  }

  const int rowBase = rowOff[g] + rb * 256;
#pragma unroll
  for (int m = 0; m < 4; ++m)
#pragma unroll
    for (int r = 0; r < 4; ++r) {
      int rl = wr + m * 16 + ((lane >> 4) << 2) + r;
      int gi = rb * 256 + rl;
      if (gi < count) {
        float sc = scale[g * TT + gi];
#pragma unroll
        for (int n = 0; n < 4; ++n) {
          int cl = wc + n * 16 + (lane & 15);
          float gv = accg[m][n][r], uv = accu[m][n][r];
          float a = gv / (1.f + __expf(-gv)) * uv * sc;
          Abuf[(size_t)(rowBase + rl) * FD + cb * 128 + cl] = f2bf(a);
        }
      }
    }
}

__global__ __launch_bounds__(512, 2) void gemm2_kernel(
    const unsigned short* __restrict__ Abuf,
    const float* __restrict__ w_down, const float* __restrict__ ws_down,
    const int* __restrict__ tok, const int* __restrict__ counts,
    const int* __restrict__ rowOff, float* __restrict__ out) {
  const int g = blockIdx.z, cb = blockIdx.y, rb = blockIdx.x;
  const int count = counts[g];
  if (rb * 256 >= count) return;

  const float* Bd = (g < NE) ? (w_down + (size_t)g * FD * HD)
                             : (ws_down + (size_t)(g - NE) * FD * HD);

  __shared__ __align__(16) unsigned short sA[2][256 * 32];
  __shared__ __align__(16) unsigned short sB[2][128 * 32];

  const int tid = threadIdx.x;
  const int lane = tid & 63;
  const int wid = tid >> 6;
  const int wr = (wid >> 1) << 6;
  const int wc = (wid & 1) << 6;

  const int rowBase = rowOff[g] + rb * 256;

  const int kg = tid & 3;
  const int rr = tid >> 2;
  const unsigned short* ap0 = Abuf + (size_t)(rowBase + rr) * FD + kg * 8;
  const unsigned short* ap1 = ap0 + (size_t)128 * FD;

  const int bc = tid & 127;
  const int kb = (tid >> 7) << 3;
  const float* bp = Bd + (size_t)kb * HD + cb * 128 + bc;

  const f32x4 fz = {0.f, 0.f, 0.f, 0.f};
  f32x4 acc[4][4];
#pragma unroll
  for (int m = 0; m < 4; ++m)
#pragma unroll
    for (int n = 0; n < 4; ++n) acc[m][n] = fz;

  u16x8 a0, a1; float bv[8];
  auto LOAD = [&](int k0) {
    a0 = *(const u16x8*)(ap0 + k0);
    a1 = *(const u16x8*)(ap1 + k0);
#pragma unroll
    for (int j = 0; j < 8; ++j) bv[j] = bp[(size_t)(k0 + j) * HD];
  };
  auto STORE = [&](int b) {
    int sw = ((kg ^ rr) & 3) << 3;
    *(u16x8*)&sA[b][rr * 32 + sw] = a0;
    *(u16x8*)&sA[b][(rr + 128) * 32 + sw] = a1;
    u16x8 hb;
#pragma unroll
    for (int j = 0; j < 8; ++j) hb[j] = f2bf(bv[j]);
    *(u16x8*)&sB[b][bc * 32 + ((((kb >> 3) ^ bc) & 3) << 3)] = hb;
  };
  auto COMPUTE = [&](int b) {
    const int ksel = lane >> 4;
    short8 b4[4];
#pragma unroll
    for (int n = 0; n < 4; ++n) {
      int c = wc + n * 16 + (lane & 15);
      b4[n] = *(const short8*)&sB[b][c * 32 + (((ksel ^ c) & 3) << 3)];
    }
#pragma unroll
    for (int m = 0; m < 4; ++m) {
      int r = wr + m * 16 + (lane & 15);
      short8 a = *(const short8*)&sA[b][r * 32 + (((ksel ^ r) & 3) << 3)];
#pragma unroll
      for (int n = 0; n < 4; ++n) acc[m][n] = mfma16(a, b4[n], acc[m][n]);
    }
  };

  LOAD(0);
  STORE(0);
  __syncthreads();
  const int NK = FD / 32;
  for (int s = 0; s < NK; ++s) {
    int cur = s & 1;
    if (s + 1 < NK) LOAD((s + 1) * 32);
    COMPUTE(cur);
    if (s + 1 < NK) STORE(cur ^ 1);
    __syncthreads();
  }

#pragma unroll
  for (int m = 0; m < 4; ++m)
#pragma unroll
    for (int r = 0; r < 4; ++r) {
      int rl = wr + m * 16 + ((lane >> 4) << 2) + r;
      int gi = rb * 256 + rl;
      if (gi < count) {
        int t = tok[g * TT + gi];
        float* op = out + (size_t)t * HD + cb * 128;
#pragma unroll
        for (int n = 0; n < 4; ++n)
          atomicAdd(op + wc + n * 16 + (lane & 15), acc[m][n][r]);
      }
    }
}

// ---------------------------------------------------------------------------
extern "C" void kernel_launch(void* const* d_in, const int* in_sizes, int n_in,
                              void* d_out, int out_size, void* d_ws, size_t ws_size,
                              hipStream_t stream) {
  const float* x      = (const float*)d_in[0];
  const float* gw     = (const float*)d_in[1];
  const float* w_gate = (const float*)d_in[2];
  const float* w_up   = (const float*)d_in[3];
  const float* w_down = (const float*)d_in[4];
  const float* wsg    = (const float*)d_in[5];
  const float* wsu    = (const float*)d_in[6];
  const float* wsd    = (const float*)d_in[7];
  float* out = (float*)d_out;

  char* ws = (char*)d_ws;
  float* dense_w = (float*)(ws);                       // 128KB
  int*   tok     = (int*)(ws + (140 << 10));           // 144KB
  float* scale   = (float*)(ws + (290 << 10));         // 144KB
  int*   counts  = (int*)(ws + (440 << 10));
  int*   rowOff  = (int*)(ws + (441 << 10));
  unsigned short* Abuf = (unsigned short*)(ws + (1 << 20));  // 33MB

  hipMemsetAsync(d_out, 0, (size_t)out_size * sizeof(float), stream);
  gate_kernel<<<TT / 4, 256, 0, stream>>>(x, gw, dense_w);
  build_lists<<<NG, 64, 0, stream>>>(dense_w, tok, scale, counts);
  prefix_kernel<<<1, 64, 0, stream>>>(counts, rowOff);

  const size_t NEED = 359ull << 20;
  if (ws_size >= NEED) {
    unsigned short* xb   = (unsigned short*)(ws + (36ull  << 20));  // 8MB
    unsigned short* wgT  = (unsigned short*)(ws + (44ull  << 20));  // 88MB
    unsigned short* wuT  = (unsigned short*)(ws + (137ull << 20));  // 88MB
    unsigned short* wdT  = (unsigned short*)(ws + (230ull << 20));  // 88MB
    unsigned short* wsgT = (unsigned short*)(ws + (323ull << 20));  // 11MB
    unsigned short* wsuT = (unsigned short*)(ws + (335ull << 20));  // 11MB
    unsigned short* wsdT = (unsigned short*)(ws + (347ull << 20));  // 11MB

    cvt_bf16_kernel<<<(TT * HD / 4 + 255) / 256, 256, 0, stream>>>(x, xb, TT * HD / 4);
    transpose_bf16_kernel<<<dim3(FD / 64, HD / 64, NE), 256, 0, stream>>>(w_gate, wgT, HD, FD);
    transpose_bf16_kernel<<<dim3(FD / 64, HD / 64, NE), 256, 0, stream>>>(w_up,   wuT, HD, FD);
    transpose_bf16_kernel<<<dim3(HD / 64, FD / 64, NE), 256, 0, stream>>>(w_down, wdT, FD, HD);
    transpose_bf16_kernel<<<dim3(2 * FD / 64, HD / 64, 1), 256, 0, stream>>>(wsg, wsgT, HD, 2 * FD);
    transpose_bf16_kernel<<<dim3(2 * FD / 64, HD / 64, 1), 256, 0, stream>>>(wsu, wsuT, HD, 2 * FD);
    transpose_bf16_kernel<<<dim3(HD / 64, 2 * FD / 64, 1), 256, 0, stream>>>(wsd, wsdT, 2 * FD, HD);

    gemm1_fast<<<dim3(8, FD / 128, NG), 512, 0, stream>>>(
        xb, wgT, wuT, wsgT, wsuT, tok, scale, counts, rowOff, Abuf);
    gemm2_fast<<<dim3(8, HD / 128, NG), 512, 0, stream>>>(
        Abuf, wdT, wsdT, tok, counts, rowOff, out);
  } else {
    gemm1_kernel<<<dim3(8, FD / 128, NG), 512, 0, stream>>>(
        x, w_gate, w_up, wsg, wsu, tok, scale, counts, rowOff, Abuf);
    gemm2_kernel<<<dim3(8, HD / 128, NG), 512, 0, stream>>>(
        Abuf, w_down, wsd, tok, counts, rowOff, out);
  }
}